// Round 9
// baseline (467.992 us; speedup 1.0000x reference)
//
#include <hip/hip_runtime.h>
#include <hip/hip_bf16.h>
#include <math.h>

#define HW 16384   // 128*128 bev pixels

typedef __attribute__((ext_vector_type(8))) short short8;
typedef __attribute__((ext_vector_type(4))) float floatx4;
typedef __attribute__((ext_vector_type(2))) float floatx2;

__device__ __forceinline__ float gelu_exact(float x){
    return 0.5f * x * (1.0f + erff(x * 0.7071067811865475f));
}

__device__ __forceinline__ floatx2 bf2x(unsigned int u){
    floatx2 r;
    r.x = __uint_as_float(u << 16);
    r.y = __uint_as_float(u & 0xffff0000u);
    return r;
}

// ---------------- all-level feat transpose: (N,C,H,W) fp32 -> (N,H,W,C) fp32 ----------------
__global__ __launch_bounds__(256) void feat_transpose_all_k(
    const float* __restrict__ f0, const float* __restrict__ f1,
    const float* __restrict__ f2, const float* __restrict__ f3,
    float* __restrict__ out)
{
    int idx = blockIdx.x * 256 + threadIdx.x;
    const float* in; int Hl, Wl, base;
    if (idx < 2162688)      { in = f0; Hl = 32; Wl = 88; base = 0; }
    else if (idx < 2703360) { in = f1; Hl = 16; Wl = 44; base = 2162688; }
    else if (idx < 2838528) { in = f2; Hl = 8;  Wl = 22; base = 2703360; }
    else                    { in = f3; Hl = 4;  Wl = 11; base = 2838528; }
    int r   = idx - base;
    int c   = r & 127;
    int pix = r >> 7;
    int x   = pix % Wl;
    int tt  = pix / Wl;
    int y   = tt % Hl;
    int n   = tt / Hl;
    out[idx] = in[((n * 128 + c) * Hl + y) * Wl + x];
}

// ---------------- unified weight prep (block-range dispatch) ----------------
__global__ __launch_bounds__(256) void prep_k(
    const float* __restrict__ mid_w1, const float* __restrict__ mid_w2,
    const float* __restrict__ mid_w3, const float* __restrict__ pe_w2,
    const float* __restrict__ off_w,  const float* __restrict__ off_b,
    const float* __restrict__ sw_w,   const float* __restrict__ sw_b,
    const float* __restrict__ in_w,   const float* __restrict__ out_w,
    __hip_bfloat16* __restrict__ Wb1, __hip_bfloat16* __restrict__ Wb2,
    __hip_bfloat16* __restrict__ Wb3, __hip_bfloat16* __restrict__ Wpe,
    __hip_bfloat16* __restrict__ Wof, float* __restrict__ Bof,
    __hip_bfloat16* __restrict__ Wcv1, __hip_bfloat16* __restrict__ Wcv2)
{
    int b = blockIdx.x, t = threadIdx.x;
    if (b < 2048) {
        int i = b * 256 + t; Wb1[i] = __float2bfloat16(mid_w1[i]);
    } else if (b < 3072) {
        int i = (b - 2048) * 256 + t; Wb2[i] = __float2bfloat16(mid_w2[i]);
    } else if (b < 3328) {
        int i = (b - 3072) * 256 + t; Wb3[i] = __float2bfloat16(mid_w3[i]);
    } else if (b < 3456) {
        int n = b - 3328; Wpe[n * 256 + t] = __float2bfloat16(pe_w2[t * 128 + n]);
    } else if (b < 3584) {
        int n = b - 3456;
        if (t < 128) {
            float w = 0.f;
            if (n < 24)      w = off_w[n * 128 + t];
            else if (n < 56) w = sw_w[(n - 24) * 128 + t];
            Wof[n * 128 + t] = __float2bfloat16(w);
            if (t == 0) Bof[n] = (n < 24) ? off_b[n] : ((n < 56) ? sw_b[n - 24] : 0.f);
        }
    } else if (b < 3712) {
        int o = b - 3584;
        for (int idx = t; idx < 1152; idx += 256) {
            int s = idx >> 7, i = idx & 127;
            Wcv1[o * 1152 + idx] = __float2bfloat16(in_w[(o * 128 + i) * 9 + s]);
        }
    } else {
        int o = b - 3712;
        for (int idx = t; idx < 1152; idx += 256) {
            int s = idx >> 7, i = idx & 127;
            Wcv2[o * 1152 + idx] = __float2bfloat16(out_w[(o * 128 + i) * 9 + s]);
        }
    }
}

// ---------------- CHW fp32 [128][128^2] -> padded HWC bf16 [130][130][128] (interior) ----------------
__global__ __launch_bounds__(256) void chw2hwc_pad_k(
    const float* __restrict__ q, __hip_bfloat16* __restrict__ out)
{
    __shared__ float tile[128][65];
    int b = blockIdx.x;            // 256 blocks: y = b>>1, x0 = (b&1)*64
    int y = b >> 1, x0 = (b & 1) * 64;
    int t = threadIdx.x;
    int xi = t & 63, c0 = t >> 6;
    for (int c = c0; c < 128; c += 4)
        tile[c][xi] = q[c * HW + y * 128 + x0 + xi];
    __syncthreads();
    int xp = t >> 2, cg = (t & 3) * 32;
    __hip_bfloat16* dst = out + ((size_t)(y + 1) * 130 + (x0 + 1 + xp)) * 128;
    #pragma unroll
    for (int g = 0; g < 4; g++) {
        int c = cg + g * 8;
        union { __hip_bfloat16 h[8]; uint4 u; } pk;
        #pragma unroll
        for (int j = 0; j < 8; j++) pk.h[j] = __float2bfloat16(tile[c + j][xp]);
        *(uint4*)&dst[c] = pk.u;
    }
}

// ---------------- bf16 MFMA GEMM: out[m][n] = act(bias[n] + sum_k X[m][k] W[n][k]) ----------------
// OUTT: 0 -> bf16 [M][N]; 1 -> fp32 [N][M] (CHW, + optional residual res[n][m]).
// CONV: X is padded HWC bf16 [130][130][128]; k = s*128+c.
template<int BM, int BN, int ACT, int OUTT, int CONV>
__global__ __launch_bounds__(256) void bgemm_k(
    const __hip_bfloat16* __restrict__ X, const __hip_bfloat16* __restrict__ W,
    const float* __restrict__ bias, void* __restrict__ outp,
    const float* __restrict__ res,
    int M, int K, int N)
{
    constexpr int ROWS = BM + BN;
    __shared__ __align__(16) __hip_bfloat16 SH[ROWS * 32];
    __hip_bfloat16* As = SH;
    __hip_bfloat16* Bs = SH + BM * 32;
    int t = threadIdx.x;
    int w = t >> 6, lane = t & 63;
    int mb = blockIdx.y * BM, nb = blockIdx.x * BN;
    int cy = mb >> 7, cx = mb & 127;   // conv tile coords (CONV only)
    constexpr int WM = BM / 2;
    constexpr int MI = WM / 16;
    constexpr int NJ = BN / 32;
    int wm = (w & 1) * WM, wn = (w >> 1) * (BN / 2);
    int lm = lane & 15, lq = lane >> 4;
    floatx4 zero = {0.f, 0.f, 0.f, 0.f};
    floatx4 acc[MI][NJ];
    #pragma unroll
    for (int i = 0; i < MI; i++)
        #pragma unroll
        for (int j = 0; j < NJ; j++) acc[i][j] = zero;
    constexpr int ITERS = (ROWS * 4) / 256;
    for (int kb = 0; kb < K; kb += 32) {
        int s = kb >> 7;
        int dyi = s / 3, dxi = s - dyi * 3;   // tap indices (CONV only)
        __syncthreads();
        #pragma unroll
        for (int it = 0; it < ITERS; it++) {
            int chunk = it * 256 + t;
            int row = chunk >> 2, ko = (chunk & 3) * 8;
            const __hip_bfloat16* src;
            if (row < BM) {
                if (CONV)
                    src = X + (((size_t)(cy + dyi) * 130) + (cx + dxi + row)) * 128 + (kb & 127) + ko;
                else
                    src = X + (size_t)(mb + row) * K + kb + ko;
            } else {
                src = W + (size_t)(nb + row - BM) * K + kb + ko;
            }
            __builtin_amdgcn_global_load_lds(
                (const __attribute__((address_space(1))) void*)src,
                (__attribute__((address_space(3))) void*)&SH[(size_t)(it * 256 + (t & ~63)) * 8],
                16, 0, 0);
        }
        __syncthreads();
        short8 af[MI], bf[NJ];
        #pragma unroll
        for (int i = 0; i < MI; i++)
            af[i] = *(const short8*)&As[(wm + i * 16 + lm) * 32 + lq * 8];
        #pragma unroll
        for (int j = 0; j < NJ; j++)
            bf[j] = *(const short8*)&Bs[(wn + j * 16 + lm) * 32 + lq * 8];
        #pragma unroll
        for (int i = 0; i < MI; i++)
            #pragma unroll
            for (int j = 0; j < NJ; j++)
                acc[i][j] = __builtin_amdgcn_mfma_f32_16x16x32_bf16(af[i], bf[j], acc[i][j], 0, 0, 0);
    }
    #pragma unroll
    for (int i = 0; i < MI; i++) {
        #pragma unroll
        for (int j = 0; j < NJ; j++) {
            int n = nb + wn + j * 16 + lm;
            float bv = bias[n];
            #pragma unroll
            for (int r = 0; r < 4; r++) {
                int m = mb + wm + i * 16 + lq * 4 + r;
                float v = acc[i][j][r] + bv;
                if (ACT) v = gelu_exact(v);
                if (OUTT == 0) {
                    ((__hip_bfloat16*)outp)[(size_t)m * N + n] = __float2bfloat16(v);
                } else {
                    if (res) v += res[(size_t)n * M + m];
                    ((float*)outp)[(size_t)n * M + m] = v;
                }
            }
        }
    }
}

// ---------------- fused PE: hidden = relu(rn @ w1 + b1) on the fly, GEMM vs Wpe ----------------
__global__ __launch_bounds__(256) void pe_bgemm_k(
    const float* __restrict__ pts, const float* __restrict__ pe_w1,
    const float* __restrict__ pe_b1, const __hip_bfloat16* __restrict__ W,
    const float* __restrict__ bias, __hip_bfloat16* __restrict__ out)
{
    __shared__ __align__(16) __hip_bfloat16 As[128 * 32];
    __shared__ __align__(16) __hip_bfloat16 Bs[128 * 32];
    __shared__ __align__(16) float wps[4][256];   // [b1, w1_x, w1_y, w1_z][256]
    int t = threadIdx.x;
    int w = t >> 6, lane = t & 63;
    int mb = blockIdx.x * 128;
    {
        int d = t >> 6, c = (t & 63) * 4;
        float4 v;
        if (d == 0) v = *(const float4*)&pe_b1[c];
        else        v = *(const float4*)&pe_w1[(d - 1) * 256 + c];
        *(float4*)&wps[d][c] = v;
    }
    int cg = t & 3;
    int r0 = t >> 2;
    float rn[2][3];
    #pragma unroll
    for (int h = 0; h < 2; h++) {
        int r = mb + r0 + h * 64;
        rn[h][0] = (pts[(size_t)r * 3 + 0] + 50.f) * 0.01f;
        rn[h][1] = (pts[(size_t)r * 3 + 1] + 50.f) * 0.01f;
        rn[h][2] = (pts[(size_t)r * 3 + 2] + 4.f) * 0.125f;
    }
    int wm = (w & 1) * 64, wn = (w >> 1) * 64;
    int lm = lane & 15, lq = lane >> 4;
    floatx4 zero = {0.f, 0.f, 0.f, 0.f};
    floatx4 acc[4][4];
    #pragma unroll
    for (int i = 0; i < 4; i++)
        #pragma unroll
        for (int j = 0; j < 4; j++) acc[i][j] = zero;
    for (int kb = 0; kb < 256; kb += 32) {
        __syncthreads();
        #pragma unroll
        for (int it = 0; it < 2; it++) {
            int chunk = it * 256 + t;
            int brow = chunk >> 2, ko = (chunk & 3) * 8;
            const __hip_bfloat16* src = W + (size_t)brow * 256 + kb + ko;
            __builtin_amdgcn_global_load_lds(
                (const __attribute__((address_space(1))) void*)src,
                (__attribute__((address_space(3))) void*)&Bs[(size_t)(it * 256 + (t & ~63)) * 8],
                16, 0, 0);
        }
        int c0 = kb + cg * 8;
        float4 bva = *(const float4*)&wps[0][c0], bvb = *(const float4*)&wps[0][c0 + 4];
        float4 wxa = *(const float4*)&wps[1][c0], wxb = *(const float4*)&wps[1][c0 + 4];
        float4 wya = *(const float4*)&wps[2][c0], wyb = *(const float4*)&wps[2][c0 + 4];
        float4 wza = *(const float4*)&wps[3][c0], wzb = *(const float4*)&wps[3][c0 + 4];
        #pragma unroll
        for (int h = 0; h < 2; h++) {
            const float* bv = (const float*)&bva;
            const float* wx = (const float*)&wxa;
            const float* wy = (const float*)&wya;
            const float* wz = (const float*)&wza;
            union { __hip_bfloat16 hh[8]; uint4 u; } pk;
            #pragma unroll
            for (int j = 0; j < 4; j++) {
                float v = bv[j] + rn[h][0] * wx[j] + rn[h][1] * wy[j] + rn[h][2] * wz[j];
                pk.hh[j] = __float2bfloat16(fmaxf(v, 0.f));
            }
            bv = (const float*)&bvb; wx = (const float*)&wxb;
            wy = (const float*)&wyb; wz = (const float*)&wzb;
            #pragma unroll
            for (int j = 0; j < 4; j++) {
                float v = bv[j] + rn[h][0] * wx[j] + rn[h][1] * wy[j] + rn[h][2] * wz[j];
                pk.hh[4 + j] = __float2bfloat16(fmaxf(v, 0.f));
            }
            *(uint4*)&As[(r0 + h * 64) * 32 + cg * 8] = pk.u;
        }
        __syncthreads();
        short8 af[4], bf[4];
        #pragma unroll
        for (int i = 0; i < 4; i++)
            af[i] = *(const short8*)&As[(wm + i * 16 + lm) * 32 + lq * 8];
        #pragma unroll
        for (int j = 0; j < 4; j++)
            bf[j] = *(const short8*)&Bs[(wn + j * 16 + lm) * 32 + lq * 8];
        #pragma unroll
        for (int i = 0; i < 4; i++)
            #pragma unroll
            for (int j = 0; j < 4; j++)
                acc[i][j] = __builtin_amdgcn_mfma_f32_16x16x32_bf16(af[i], bf[j], acc[i][j], 0, 0, 0);
    }
    #pragma unroll
    for (int i = 0; i < 4; i++) {
        #pragma unroll
        for (int j = 0; j < 4; j++) {
            int n = wn + j * 16 + lm;
            float bv = bias[n];
            #pragma unroll
            for (int r = 0; r < 4; r++) {
                int m = mb + wm + i * 16 + lq * 4 + r;
                out[(size_t)m * 128 + n] = __float2bfloat16(acc[i][j][r] + bv);
            }
        }
    }
}

// ---------------- instance norm over HW per channel ----------------
__global__ __launch_bounds__(256) void inorm_k(
    const float* __restrict__ a, const float* __restrict__ addc, float* __restrict__ out)
{
    int c = blockIdx.x;
    const float* pa = a + (size_t)c * HW;
    const float* pb = addc ? addc + (size_t)c * HW : nullptr;
    const bool hasb = (pb != nullptr);
    float s = 0.f, s2 = 0.f;
    for (int i = threadIdx.x; i < HW; i += 256) {
        float v = hasb ? (pa[i] + pb[i]) : pa[i];
        s += v; s2 += v * v;
    }
    #pragma unroll
    for (int off = 32; off > 0; off >>= 1) {
        s  += __shfl_down(s,  off);
        s2 += __shfl_down(s2, off);
    }
    __shared__ float ls[4], ls2[4], stats[2];
    int wid = threadIdx.x >> 6, lane = threadIdx.x & 63;
    if (lane == 0) { ls[wid] = s; ls2[wid] = s2; }
    __syncthreads();
    if (threadIdx.x == 0) {
        float t = 0.f, t2 = 0.f;
        for (int i = 0; i < 4; i++) { t += ls[i]; t2 += ls2[i]; }
        float mean = t * (1.0f / HW);
        float var  = t2 * (1.0f / HW) - mean * mean;
        stats[0] = mean;
        stats[1] = rsqrtf(var + 1e-5f);
    }
    __syncthreads();
    float mean = stats[0], rstd = stats[1];
    float* po = out + (size_t)c * HW;
    for (int i = threadIdx.x; i < HW; i += 256) {
        float v = hasb ? (pa[i] + pb[i]) : pa[i];
        po[i] = (v - mean) * rstd;
    }
}

// ---------------- offsw epilogue: raw [n][16384] fp32 -> pts/swn/height ----------------
__global__ __launch_bounds__(256) void offpost_k(
    const float* __restrict__ raw, const float* __restrict__ bev_pos,
    float* __restrict__ pts, float* __restrict__ swn, float* __restrict__ height_out)
{
    int pix = blockIdx.x * 256 + threadIdx.x;
    const float pcmin[3] = {-50.f, -50.f, -4.f};
    const float rng[3]   = {100.f, 100.f, 8.f};
    float bp[3];
    #pragma unroll
    for (int d = 0; d < 3; d++) bp[d] = bev_pos[pix * 3 + d];
    #pragma unroll
    for (int p = 0; p < 8; p++) {
        #pragma unroll
        for (int d = 0; d < 3; d++) {
            float acc = raw[(p * 3 + d) * HW + pix];
            float sv = 1.f / (1.f + expf(-acc));
            float lim = (d == 2) ? (4.0f + 1e-6f) : (0.25f + 1e-6f);
            float offv = sv * 2.f * lim - lim;
            float refv = bp[d] * rng[d] + pcmin[d];
            pts[pix * 24 + p * 3 + d] = refv + offv;
            if (d == 2) height_out[p * HW + pix] = offv;
        }
        float r[4], m = -1e30f;
        #pragma unroll
        for (int l = 0; l < 4; l++) {
            r[l] = raw[(24 + p * 4 + l) * HW + pix];
            m = fmaxf(m, r[l]);
        }
        float sum = 0.f;
        #pragma unroll
        for (int l = 0; l < 4; l++) { r[l] = expf(r[l] - m); sum += r[l]; }
        float inv = 1.f / sum;
        #pragma unroll
        for (int l = 0; l < 4; l++) swn[pix * 32 + p * 4 + l] = r[l] * inv;
    }
}

// ---------------- sampling: phase-1 projection + cull, phase-2 fp32 packed gather ----------------
__global__ __launch_bounds__(128) void sample_k(
    const float* __restrict__ featT, const float* __restrict__ pts,
    const float* __restrict__ swn,   const float* __restrict__ l2i,
    __hip_bfloat16* __restrict__ sf)
{
    int pix = blockIdx.x;
    int t = threadIdx.x;
    int lane = t & 63, wv = t >> 6;
    __shared__ float pts_s[24];
    __shared__ float swl_s[32];
    __shared__ float M[96];
    __shared__ __align__(16) int   offs[8][24][4];
    __shared__ __align__(16) float wts[8][24][4];
    __shared__ int cnt[8];
    if (t < 96) M[t] = l2i[t];
    if (t < 24) pts_s[t] = pts[pix * 24 + t];
    if (t < 32) swl_s[t] = swn[pix * 32 + t];
    if (t < 8)  cnt[t] = 0;
    __syncthreads();

    floatx2 acc[4];
    #pragma unroll
    for (int i = 0; i < 4; i++) {
        unsigned int u = *(const unsigned int*)&sf[(size_t)pix * 1024 + (wv * 4 + i) * 128 + 2 * lane];
        acc[i] = bf2x(u);
    }

    const int lHt[4] = {32, 16, 8, 4}, lWt[4] = {88, 44, 22, 11};
    const int loff[4] = {0, 2162688, 2703360, 2838528};
    for (int cb = t; cb < 192; cb += 128) {
        int p = cb / 24;
        int rr = cb - p * 24;
        int n = rr >> 2, l = rr & 3;
        float X = pts_s[p * 3], Y = pts_s[p * 3 + 1], Z = pts_s[p * 3 + 2];
        const float* Mn = &M[n * 16];
        float zc = Mn[8] * X + Mn[9] * Y + Mn[10] * Z + Mn[11];
        if (zc > 1e-5f) {
            float inv = 1.f / zc;
            float xn = (Mn[0] * X + Mn[1] * Y + Mn[2] * Z + Mn[3]) * inv * (1.f / 704.f);
            float yn = (Mn[4] * X + Mn[5] * Y + Mn[6] * Z + Mn[7]) * inv * (1.f / 256.f);
            int Wl = lWt[l], Hl = lHt[l];
            float px = xn * Wl - 0.5f, py = yn * Hl - 0.5f;
            px = fminf(fmaxf(px, -2.f), (float)(Wl + 1));
            py = fminf(fmaxf(py, -2.f), (float)(Hl + 1));
            float x0f = floorf(px), y0f = floorf(py);
            float wx = px - x0f, wy = py - y0f;
            int x0 = (int)x0f, y0 = (int)y0f;
            bool xi0 = (unsigned)x0 < (unsigned)Wl, xi1 = (unsigned)(x0 + 1) < (unsigned)Wl;
            bool yi0 = (unsigned)y0 < (unsigned)Hl, yi1 = (unsigned)(y0 + 1) < (unsigned)Hl;
            if ((xi0 || xi1) && (yi0 || yi1)) {
                float wl = swl_s[p * 4 + l];
                float w00 = wl * (1.f - wx) * (1.f - wy) * (float)(xi0 && yi0);
                float w10 = wl * wx * (1.f - wy)         * (float)(xi1 && yi0);
                float w01 = wl * (1.f - wx) * wy         * (float)(xi0 && yi1);
                float w11 = wl * wx * wy                 * (float)(xi1 && yi1);
                int x0c = min(max(x0, 0), Wl - 1), x1c = min(max(x0 + 1, 0), Wl - 1);
                int y0c = min(max(y0, 0), Hl - 1), y1c = min(max(y0 + 1, 0), Hl - 1);
                int base = loff[l] + n * Hl * Wl * 128;
                int idx = atomicAdd(&cnt[p], 1);
                offs[p][idx][0] = base + (y0c * Wl + x0c) * 128;
                offs[p][idx][1] = base + (y0c * Wl + x1c) * 128;
                offs[p][idx][2] = base + (y1c * Wl + x0c) * 128;
                offs[p][idx][3] = base + (y1c * Wl + x1c) * 128;
                wts[p][idx][0] = w00; wts[p][idx][1] = w10;
                wts[p][idx][2] = w01; wts[p][idx][3] = w11;
            }
        }
    }
    __syncthreads();

    #pragma unroll 1
    for (int i = 0; i < 4; i++) {
        int p = wv * 4 + i;
        int np = cnt[p];
        floatx2 a = acc[i];
        #pragma unroll 1
        for (int j = 0; j < np; j++) {
            int4   o = *(const int4*)&offs[p][j][0];
            float4 w = *(const float4*)&wts[p][j][0];
            floatx2 f0 = ((const floatx2*)(featT + o.x))[lane];
            floatx2 f1 = ((const floatx2*)(featT + o.y))[lane];
            floatx2 f2 = ((const floatx2*)(featT + o.z))[lane];
            floatx2 f3 = ((const floatx2*)(featT + o.w))[lane];
            a += f0 * w.x;
            a += f1 * w.y;
            a += f2 * w.z;
            a += f3 * w.w;
        }
        acc[i] = a;
    }
    #pragma unroll
    for (int i = 0; i < 4; i++) {
        union { __hip_bfloat16 h[2]; unsigned int u; } pk;
        pk.h[0] = __float2bfloat16(acc[i].x);
        pk.h[1] = __float2bfloat16(acc[i].y);
        *(unsigned int*)&sf[(size_t)pix * 1024 + (wv * 4 + i) * 128 + 2 * lane] = pk.u;
    }
}

extern "C" void kernel_launch(void* const* d_in, const int* in_sizes, int n_in,
                              void* d_out, int out_size, void* d_ws, size_t ws_size,
                              hipStream_t stream)
{
    const float* feat[4] = {(const float*)d_in[0], (const float*)d_in[1],
                            (const float*)d_in[2], (const float*)d_in[3]};
    const float* l2i       = (const float*)d_in[4];
    const float* bev_query = (const float*)d_in[5];
    const float* bev_pos   = (const float*)d_in[6];
    const float* in_w  = (const float*)d_in[7];  const float* in_b  = (const float*)d_in[8];
    const float* off_w = (const float*)d_in[9];  const float* off_b = (const float*)d_in[10];
    const float* sw_w  = (const float*)d_in[11]; const float* sw_b  = (const float*)d_in[12];
    const float* pe_w1 = (const float*)d_in[13]; const float* pe_b1 = (const float*)d_in[14];
    const float* pe_w2 = (const float*)d_in[15]; const float* pe_b2 = (const float*)d_in[16];
    const float* mid_w1 = (const float*)d_in[17]; const float* mid_b1 = (const float*)d_in[18];
    const float* mid_w2 = (const float*)d_in[19]; const float* mid_b2 = (const float*)d_in[20];
    const float* mid_w3 = (const float*)d_in[21]; const float* mid_b3 = (const float*)d_in[22];
    const float* out_w  = (const float*)d_in[23]; const float* out_b  = (const float*)d_in[24];

    float* ws = (float*)d_ws;
    float* fT  = ws;                    // 2,872,320 : transposed feats fp32
    float* Bb  = fT + 2872320;          // 2,097,152 : conv out / offsw raw / m3 (CHW)
    float* Cb  = Bb + 2097152;          // 2,097,152 : q0 / conv2 out
    float* Gb  = Cb + 2097152;          // 2,097,152 : q1 (CHW)
    float* Dp  = Gb + 2097152;          //   393,216 : pts
    float* Eb  = Dp + 393216;           //   524,288 : swn
    float* QTf = Eb + 524288;           // 1,081,600 : padded HWC bf16 (130*130*128)
    __hip_bfloat16* qT = (__hip_bfloat16*)QTf;
    float* SFf = QTf + 1081600;         // 8,388,608 : sf bf16 131072x128
    __hip_bfloat16* sfb = (__hip_bfloat16*)SFf;
    float* M1f = SFf + 8388608;         // 4,194,304 : m1 bf16
    __hip_bfloat16* m1b = (__hip_bfloat16*)M1f;
    float* M2f = M1f + 4194304;         // 4,194,304 : m2 bf16
    __hip_bfloat16* m2b = (__hip_bfloat16*)M2f;
    float* WC1 = M2f + 4194304;         //    73,728 : conv1 weights bf16
    __hip_bfloat16* Wcv1 = (__hip_bfloat16*)WC1;
    float* WC2 = WC1 + 73728;           //    73,728 : conv2 weights bf16
    __hip_bfloat16* Wcv2 = (__hip_bfloat16*)WC2;
    float* W1f = WC2 + 73728;           //   262,144
    __hip_bfloat16* Wb1 = (__hip_bfloat16*)W1f;
    float* W2f = W1f + 262144;          //   131,072
    __hip_bfloat16* Wb2 = (__hip_bfloat16*)W2f;
    float* W3f = W2f + 131072;          //    32,768
    __hip_bfloat16* Wb3 = (__hip_bfloat16*)W3f;
    float* WPf = W3f + 32768;           //    16,384 : pe_w2^T bf16
    __hip_bfloat16* Wpe = (__hip_bfloat16*)WPf;
    float* WOf = WPf + 16384;           //     8,192 : offsw packed weight bf16
    __hip_bfloat16* Wof = (__hip_bfloat16*)WOf;
    float* Bof = WOf + 8192;            //       128 : offsw packed bias fp32

    float* q_out = (float*)d_out;
    float* h_out = q_out + 2097152;

    hipMemsetAsync(qT, 0, (size_t)130 * 130 * 128 * sizeof(__hip_bfloat16), stream);

    feat_transpose_all_k<<<11220, 256, 0, stream>>>(feat[0], feat[1], feat[2], feat[3], fT);
    prep_k<<<3840, 256, 0, stream>>>(mid_w1, mid_w2, mid_w3, pe_w2, off_w, off_b, sw_w, sw_b,
                                     in_w, out_w, Wb1, Wb2, Wb3, Wpe, Wof, Bof, Wcv1, Wcv2);

    // conv1: q0 = inorm(bev_query + conv3x3(bev_query))
    chw2hwc_pad_k<<<256, 256, 0, stream>>>(bev_query, qT);
    bgemm_k<64, 64, 0, 1, 1><<<dim3(2, 256), 256, 0, stream>>>(qT, Wcv1, in_b, Bb, bev_query, HW, 1152, 128);
    inorm_k<<<128, 256, 0, stream>>>(Bb, nullptr, Cb);

    // offsets/sample-weights GEMM over center tap of padded q0 + epilogue
    chw2hwc_pad_k<<<256, 256, 0, stream>>>(Cb, qT);
    bgemm_k<64, 64, 0, 1, 1><<<dim3(2, 256), 256, 0, stream>>>(qT + 131 * 128, Wof, Bof, Bb, nullptr, HW, 128, 128);
    offpost_k<<<64, 256, 0, stream>>>(Bb, bev_pos, Dp, Eb, h_out);

    // fused PE (hidden on the fly + MFMA GEMM) -> sf
    pe_bgemm_k<<<1024, 256, 0, stream>>>(Dp, pe_w1, pe_b1, Wpe, pe_b2, sfb);

    // sampling accumulates taps onto sf
    sample_k<<<HW, 128, 0, stream>>>(fT, Dp, Eb, l2i, sfb);

    // mid MLP: 1024 -> 512 gelu -> 512 gelu -> 128 linear (CHW fp32, +q0 residual)
    bgemm_k<128, 128, 1, 0, 0><<<dim3(4, 128), 256, 0, stream>>>(sfb, Wb1, mid_b1, m1b, nullptr, HW, 1024, 512);
    bgemm_k<128, 128, 1, 0, 0><<<dim3(4, 128), 256, 0, stream>>>(m1b, Wb2, mid_b2, m2b, nullptr, HW, 512, 512);
    bgemm_k<64, 64, 0, 1, 0><<<dim3(2, 256), 256, 0, stream>>>(m2b, Wb3, mid_b3, Bb, Cb, HW, 512, 128);
    inorm_k<<<128, 256, 0, stream>>>(Bb, nullptr, Gb);

    // conv2: q = inorm(q1 + conv3x3(q1))
    chw2hwc_pad_k<<<256, 256, 0, stream>>>(Gb, qT);
    bgemm_k<64, 64, 0, 1, 1><<<dim3(2, 256), 256, 0, stream>>>(qT, Wcv2, out_b, Cb, Gb, HW, 1152, 128);
    inorm_k<<<128, 256, 0, stream>>>(Cb, nullptr, q_out);
}

// Round 10
// 443.010 us; speedup vs baseline: 1.0564x; 1.0564x over previous
//
#include <hip/hip_runtime.h>
#include <hip/hip_bf16.h>
#include <math.h>

#define HW 16384   // 128*128 bev pixels

typedef __attribute__((ext_vector_type(8))) short short8;
typedef __attribute__((ext_vector_type(4))) float floatx4;
typedef __attribute__((ext_vector_type(2))) float floatx2;

__device__ __forceinline__ float gelu_exact(float x){
    return 0.5f * x * (1.0f + erff(x * 0.7071067811865475f));
}

__device__ __forceinline__ floatx2 bf2x(unsigned int u){
    floatx2 r;
    r.x = __uint_as_float(u << 16);
    r.y = __uint_as_float(u & 0xffff0000u);
    return r;
}

// ---------------- all-level feat transpose: (N,C,H,W) fp32 -> (N,H,W,C) bf16 ----------------
__global__ __launch_bounds__(256) void feat_transpose_all_k(
    const float* __restrict__ f0, const float* __restrict__ f1,
    const float* __restrict__ f2, const float* __restrict__ f3,
    __hip_bfloat16* __restrict__ out)
{
    int idx = blockIdx.x * 256 + threadIdx.x;
    const float* in; int Hl, Wl, base;
    if (idx < 2162688)      { in = f0; Hl = 32; Wl = 88; base = 0; }
    else if (idx < 2703360) { in = f1; Hl = 16; Wl = 44; base = 2162688; }
    else if (idx < 2838528) { in = f2; Hl = 8;  Wl = 22; base = 2703360; }
    else                    { in = f3; Hl = 4;  Wl = 11; base = 2838528; }
    int r   = idx - base;
    int c   = r & 127;
    int pix = r >> 7;
    int x   = pix % Wl;
    int tt  = pix / Wl;
    int y   = tt % Hl;
    int n   = tt / Hl;
    out[idx] = __float2bfloat16(in[((n * 128 + c) * Hl + y) * Wl + x]);
}

// ---------------- unified weight prep (block-range dispatch) ----------------
__global__ __launch_bounds__(256) void prep_k(
    const float* __restrict__ mid_w1, const float* __restrict__ mid_w2,
    const float* __restrict__ mid_w3, const float* __restrict__ pe_w2,
    const float* __restrict__ off_w,  const float* __restrict__ off_b,
    const float* __restrict__ sw_w,   const float* __restrict__ sw_b,
    const float* __restrict__ in_w,   const float* __restrict__ out_w,
    __hip_bfloat16* __restrict__ Wb1, __hip_bfloat16* __restrict__ Wb2,
    __hip_bfloat16* __restrict__ Wb3, __hip_bfloat16* __restrict__ Wpe,
    __hip_bfloat16* __restrict__ Wof, float* __restrict__ Bof,
    __hip_bfloat16* __restrict__ Wcv1, __hip_bfloat16* __restrict__ Wcv2)
{
    int b = blockIdx.x, t = threadIdx.x;
    if (b < 2048) {
        int i = b * 256 + t; Wb1[i] = __float2bfloat16(mid_w1[i]);
    } else if (b < 3072) {
        int i = (b - 2048) * 256 + t; Wb2[i] = __float2bfloat16(mid_w2[i]);
    } else if (b < 3328) {
        int i = (b - 3072) * 256 + t; Wb3[i] = __float2bfloat16(mid_w3[i]);
    } else if (b < 3456) {
        int n = b - 3328; Wpe[n * 256 + t] = __float2bfloat16(pe_w2[t * 128 + n]);
    } else if (b < 3584) {
        int n = b - 3456;
        if (t < 128) {
            float w = 0.f;
            if (n < 24)      w = off_w[n * 128 + t];
            else if (n < 56) w = sw_w[(n - 24) * 128 + t];
            Wof[n * 128 + t] = __float2bfloat16(w);
            if (t == 0) Bof[n] = (n < 24) ? off_b[n] : ((n < 56) ? sw_b[n - 24] : 0.f);
        }
    } else if (b < 3712) {
        int o = b - 3584;
        for (int idx = t; idx < 1152; idx += 256) {
            int s = idx >> 7, i = idx & 127;
            Wcv1[o * 1152 + idx] = __float2bfloat16(in_w[(o * 128 + i) * 9 + s]);
        }
    } else {
        int o = b - 3712;
        for (int idx = t; idx < 1152; idx += 256) {
            int s = idx >> 7, i = idx & 127;
            Wcv2[o * 1152 + idx] = __float2bfloat16(out_w[(o * 128 + i) * 9 + s]);
        }
    }
}

// ---------------- CHW fp32 [128][128^2] -> padded HWC bf16 [130][130][128] (interior) ----------------
__global__ __launch_bounds__(256) void chw2hwc_pad_k(
    const float* __restrict__ q, __hip_bfloat16* __restrict__ out)
{
    __shared__ float tile[128][65];
    int b = blockIdx.x;            // 256 blocks: y = b>>1, x0 = (b&1)*64
    int y = b >> 1, x0 = (b & 1) * 64;
    int t = threadIdx.x;
    int xi = t & 63, c0 = t >> 6;
    for (int c = c0; c < 128; c += 4)
        tile[c][xi] = q[c * HW + y * 128 + x0 + xi];
    __syncthreads();
    int xp = t >> 2, cg = (t & 3) * 32;
    __hip_bfloat16* dst = out + ((size_t)(y + 1) * 130 + (x0 + 1 + xp)) * 128;
    #pragma unroll
    for (int g = 0; g < 4; g++) {
        int c = cg + g * 8;
        union { __hip_bfloat16 h[8]; uint4 u; } pk;
        #pragma unroll
        for (int j = 0; j < 8; j++) pk.h[j] = __float2bfloat16(tile[c + j][xp]);
        *(uint4*)&dst[c] = pk.u;
    }
}

// ---------------- bf16 MFMA GEMM: out[m][n] = act(bias[n] + sum_k X[m][k] W[n][k]) ----------------
// OUTT: 0 -> bf16 [M][N]; 1 -> fp32 [N][M] (CHW, + optional residual res[n][m]).
// CONV: X is padded HWC bf16 [130][130][128]; k = s*128+c.
template<int BM, int BN, int ACT, int OUTT, int CONV>
__global__ __launch_bounds__(256) void bgemm_k(
    const __hip_bfloat16* __restrict__ X, const __hip_bfloat16* __restrict__ W,
    const float* __restrict__ bias, void* __restrict__ outp,
    const float* __restrict__ res,
    int M, int K, int N)
{
    constexpr int ROWS = BM + BN;
    __shared__ __align__(16) __hip_bfloat16 SH[ROWS * 32];
    __hip_bfloat16* As = SH;
    __hip_bfloat16* Bs = SH + BM * 32;
    int t = threadIdx.x;
    int w = t >> 6, lane = t & 63;
    int mb = blockIdx.y * BM, nb = blockIdx.x * BN;
    int cy = mb >> 7, cx = mb & 127;   // conv tile coords (CONV only)
    constexpr int WM = BM / 2;
    constexpr int MI = WM / 16;
    constexpr int NJ = BN / 32;
    int wm = (w & 1) * WM, wn = (w >> 1) * (BN / 2);
    int lm = lane & 15, lq = lane >> 4;
    floatx4 zero = {0.f, 0.f, 0.f, 0.f};
    floatx4 acc[MI][NJ];
    #pragma unroll
    for (int i = 0; i < MI; i++)
        #pragma unroll
        for (int j = 0; j < NJ; j++) acc[i][j] = zero;
    constexpr int ITERS = (ROWS * 4) / 256;
    for (int kb = 0; kb < K; kb += 32) {
        int s = kb >> 7;
        int dyi = s / 3, dxi = s - dyi * 3;   // tap indices (CONV only)
        __syncthreads();
        #pragma unroll
        for (int it = 0; it < ITERS; it++) {
            int chunk = it * 256 + t;
            int row = chunk >> 2, ko = (chunk & 3) * 8;
            const __hip_bfloat16* src;
            if (row < BM) {
                if (CONV)
                    src = X + (((size_t)(cy + dyi) * 130) + (cx + dxi + row)) * 128 + (kb & 127) + ko;
                else
                    src = X + (size_t)(mb + row) * K + kb + ko;
            } else {
                src = W + (size_t)(nb + row - BM) * K + kb + ko;
            }
            __builtin_amdgcn_global_load_lds(
                (const __attribute__((address_space(1))) void*)src,
                (__attribute__((address_space(3))) void*)&SH[(size_t)(it * 256 + (t & ~63)) * 8],
                16, 0, 0);
        }
        __syncthreads();
        short8 af[MI], bf[NJ];
        #pragma unroll
        for (int i = 0; i < MI; i++)
            af[i] = *(const short8*)&As[(wm + i * 16 + lm) * 32 + lq * 8];
        #pragma unroll
        for (int j = 0; j < NJ; j++)
            bf[j] = *(const short8*)&Bs[(wn + j * 16 + lm) * 32 + lq * 8];
        #pragma unroll
        for (int i = 0; i < MI; i++)
            #pragma unroll
            for (int j = 0; j < NJ; j++)
                acc[i][j] = __builtin_amdgcn_mfma_f32_16x16x32_bf16(af[i], bf[j], acc[i][j], 0, 0, 0);
    }
    #pragma unroll
    for (int i = 0; i < MI; i++) {
        #pragma unroll
        for (int j = 0; j < NJ; j++) {
            int n = nb + wn + j * 16 + lm;
            float bv = bias[n];
            #pragma unroll
            for (int r = 0; r < 4; r++) {
                int m = mb + wm + i * 16 + lq * 4 + r;
                float v = acc[i][j][r] + bv;
                if (ACT) v = gelu_exact(v);
                if (OUTT == 0) {
                    ((__hip_bfloat16*)outp)[(size_t)m * N + n] = __float2bfloat16(v);
                } else {
                    if (res) v += res[(size_t)n * M + m];
                    ((float*)outp)[(size_t)n * M + m] = v;
                }
            }
        }
    }
}

// ---------------- fused PE: hidden = relu(rn @ w1 + b1) on the fly, GEMM vs Wpe ----------------
__global__ __launch_bounds__(256) void pe_bgemm_k(
    const float* __restrict__ pts, const float* __restrict__ pe_w1,
    const float* __restrict__ pe_b1, const __hip_bfloat16* __restrict__ W,
    const float* __restrict__ bias, __hip_bfloat16* __restrict__ out)
{
    __shared__ __align__(16) __hip_bfloat16 As[128 * 32];
    __shared__ __align__(16) __hip_bfloat16 Bs[128 * 32];
    __shared__ __align__(16) float wps[4][256];   // [b1, w1_x, w1_y, w1_z][256]
    int t = threadIdx.x;
    int w = t >> 6, lane = t & 63;
    int mb = blockIdx.x * 128;
    {
        int d = t >> 6, c = (t & 63) * 4;
        float4 v;
        if (d == 0) v = *(const float4*)&pe_b1[c];
        else        v = *(const float4*)&pe_w1[(d - 1) * 256 + c];
        *(float4*)&wps[d][c] = v;
    }
    int cg = t & 3;
    int r0 = t >> 2;
    float rn[2][3];
    #pragma unroll
    for (int h = 0; h < 2; h++) {
        int r = mb + r0 + h * 64;
        rn[h][0] = (pts[(size_t)r * 3 + 0] + 50.f) * 0.01f;
        rn[h][1] = (pts[(size_t)r * 3 + 1] + 50.f) * 0.01f;
        rn[h][2] = (pts[(size_t)r * 3 + 2] + 4.f) * 0.125f;
    }
    int wm = (w & 1) * 64, wn = (w >> 1) * 64;
    int lm = lane & 15, lq = lane >> 4;
    floatx4 zero = {0.f, 0.f, 0.f, 0.f};
    floatx4 acc[4][4];
    #pragma unroll
    for (int i = 0; i < 4; i++)
        #pragma unroll
        for (int j = 0; j < 4; j++) acc[i][j] = zero;
    for (int kb = 0; kb < 256; kb += 32) {
        __syncthreads();
        #pragma unroll
        for (int it = 0; it < 2; it++) {
            int chunk = it * 256 + t;
            int brow = chunk >> 2, ko = (chunk & 3) * 8;
            const __hip_bfloat16* src = W + (size_t)brow * 256 + kb + ko;
            __builtin_amdgcn_global_load_lds(
                (const __attribute__((address_space(1))) void*)src,
                (__attribute__((address_space(3))) void*)&Bs[(size_t)(it * 256 + (t & ~63)) * 8],
                16, 0, 0);
        }
        int c0 = kb + cg * 8;
        float4 bva = *(const float4*)&wps[0][c0], bvb = *(const float4*)&wps[0][c0 + 4];
        float4 wxa = *(const float4*)&wps[1][c0], wxb = *(const float4*)&wps[1][c0 + 4];
        float4 wya = *(const float4*)&wps[2][c0], wyb = *(const float4*)&wps[2][c0 + 4];
        float4 wza = *(const float4*)&wps[3][c0], wzb = *(const float4*)&wps[3][c0 + 4];
        #pragma unroll
        for (int h = 0; h < 2; h++) {
            const float* bv = (const float*)&bva;
            const float* wx = (const float*)&wxa;
            const float* wy = (const float*)&wya;
            const float* wz = (const float*)&wza;
            union { __hip_bfloat16 hh[8]; uint4 u; } pk;
            #pragma unroll
            for (int j = 0; j < 4; j++) {
                float v = bv[j] + rn[h][0] * wx[j] + rn[h][1] * wy[j] + rn[h][2] * wz[j];
                pk.hh[j] = __float2bfloat16(fmaxf(v, 0.f));
            }
            bv = (const float*)&bvb; wx = (const float*)&wxb;
            wy = (const float*)&wyb; wz = (const float*)&wzb;
            #pragma unroll
            for (int j = 0; j < 4; j++) {
                float v = bv[j] + rn[h][0] * wx[j] + rn[h][1] * wy[j] + rn[h][2] * wz[j];
                pk.hh[4 + j] = __float2bfloat16(fmaxf(v, 0.f));
            }
            *(uint4*)&As[(r0 + h * 64) * 32 + cg * 8] = pk.u;
        }
        __syncthreads();
        short8 af[4], bf[4];
        #pragma unroll
        for (int i = 0; i < 4; i++)
            af[i] = *(const short8*)&As[(wm + i * 16 + lm) * 32 + lq * 8];
        #pragma unroll
        for (int j = 0; j < 4; j++)
            bf[j] = *(const short8*)&Bs[(wn + j * 16 + lm) * 32 + lq * 8];
        #pragma unroll
        for (int i = 0; i < 4; i++)
            #pragma unroll
            for (int j = 0; j < 4; j++)
                acc[i][j] = __builtin_amdgcn_mfma_f32_16x16x32_bf16(af[i], bf[j], acc[i][j], 0, 0, 0);
    }
    #pragma unroll
    for (int i = 0; i < 4; i++) {
        #pragma unroll
        for (int j = 0; j < 4; j++) {
            int n = wn + j * 16 + lm;
            float bv = bias[n];
            #pragma unroll
            for (int r = 0; r < 4; r++) {
                int m = mb + wm + i * 16 + lq * 4 + r;
                out[(size_t)m * 128 + n] = __float2bfloat16(acc[i][j][r] + bv);
            }
        }
    }
}

// ---------------- instance norm over HW per channel ----------------
__global__ __launch_bounds__(256) void inorm_k(
    const float* __restrict__ a, const float* __restrict__ addc, float* __restrict__ out)
{
    int c = blockIdx.x;
    const float* pa = a + (size_t)c * HW;
    const float* pb = addc ? addc + (size_t)c * HW : nullptr;
    const bool hasb = (pb != nullptr);
    float s = 0.f, s2 = 0.f;
    for (int i = threadIdx.x; i < HW; i += 256) {
        float v = hasb ? (pa[i] + pb[i]) : pa[i];
        s += v; s2 += v * v;
    }
    #pragma unroll
    for (int off = 32; off > 0; off >>= 1) {
        s  += __shfl_down(s,  off);
        s2 += __shfl_down(s2, off);
    }
    __shared__ float ls[4], ls2[4], stats[2];
    int wid = threadIdx.x >> 6, lane = threadIdx.x & 63;
    if (lane == 0) { ls[wid] = s; ls2[wid] = s2; }
    __syncthreads();
    if (threadIdx.x == 0) {
        float t = 0.f, t2 = 0.f;
        for (int i = 0; i < 4; i++) { t += ls[i]; t2 += ls2[i]; }
        float mean = t * (1.0f / HW);
        float var  = t2 * (1.0f / HW) - mean * mean;
        stats[0] = mean;
        stats[1] = rsqrtf(var + 1e-5f);
    }
    __syncthreads();
    float mean = stats[0], rstd = stats[1];
    float* po = out + (size_t)c * HW;
    for (int i = threadIdx.x; i < HW; i += 256) {
        float v = hasb ? (pa[i] + pb[i]) : pa[i];
        po[i] = (v - mean) * rstd;
    }
}

// ---------------- offsw epilogue: raw [n][16384] fp32 -> pts/swn/height ----------------
__global__ __launch_bounds__(256) void offpost_k(
    const float* __restrict__ raw, const float* __restrict__ bev_pos,
    float* __restrict__ pts, float* __restrict__ swn, float* __restrict__ height_out)
{
    int pix = blockIdx.x * 256 + threadIdx.x;
    const float pcmin[3] = {-50.f, -50.f, -4.f};
    const float rng[3]   = {100.f, 100.f, 8.f};
    float bp[3];
    #pragma unroll
    for (int d = 0; d < 3; d++) bp[d] = bev_pos[pix * 3 + d];
    #pragma unroll
    for (int p = 0; p < 8; p++) {
        #pragma unroll
        for (int d = 0; d < 3; d++) {
            float acc = raw[(p * 3 + d) * HW + pix];
            float sv = 1.f / (1.f + expf(-acc));
            float lim = (d == 2) ? (4.0f + 1e-6f) : (0.25f + 1e-6f);
            float offv = sv * 2.f * lim - lim;
            float refv = bp[d] * rng[d] + pcmin[d];
            pts[pix * 24 + p * 3 + d] = refv + offv;
            if (d == 2) height_out[p * HW + pix] = offv;
        }
        float r[4], m = -1e30f;
        #pragma unroll
        for (int l = 0; l < 4; l++) {
            r[l] = raw[(24 + p * 4 + l) * HW + pix];
            m = fmaxf(m, r[l]);
        }
        float sum = 0.f;
        #pragma unroll
        for (int l = 0; l < 4; l++) { r[l] = expf(r[l] - m); sum += r[l]; }
        float inv = 1.f / sum;
        #pragma unroll
        for (int l = 0; l < 4; l++) swn[pix * 32 + p * 4 + l] = r[l] * inv;
    }
}

// ---------------- sampling: phase-1 projection + cull, phase-2 bf16 packed gather ----------------
__global__ __launch_bounds__(128) void sample_k(
    const __hip_bfloat16* __restrict__ featT, const float* __restrict__ pts,
    const float* __restrict__ swn,   const float* __restrict__ l2i,
    __hip_bfloat16* __restrict__ sf)
{
    int pix = blockIdx.x;
    int t = threadIdx.x;
    int lane = t & 63, wv = t >> 6;
    __shared__ float pts_s[24];
    __shared__ float swl_s[32];
    __shared__ float M[96];
    __shared__ __align__(16) int   offs[8][24][4];
    __shared__ __align__(16) float wts[8][24][4];
    __shared__ int cnt[8];
    if (t < 96) M[t] = l2i[t];
    if (t < 24) pts_s[t] = pts[pix * 24 + t];
    if (t < 32) swl_s[t] = swn[pix * 32 + t];
    if (t < 8)  cnt[t] = 0;
    __syncthreads();

    floatx2 acc[4];
    #pragma unroll
    for (int i = 0; i < 4; i++) {
        unsigned int u = *(const unsigned int*)&sf[(size_t)pix * 1024 + (wv * 4 + i) * 128 + 2 * lane];
        acc[i] = bf2x(u);
    }

    const int lHt[4] = {32, 16, 8, 4}, lWt[4] = {88, 44, 22, 11};
    const int loff[4] = {0, 2162688, 2703360, 2838528};
    for (int cb = t; cb < 192; cb += 128) {
        int p = cb / 24;
        int rr = cb - p * 24;
        int n = rr >> 2, l = rr & 3;
        float X = pts_s[p * 3], Y = pts_s[p * 3 + 1], Z = pts_s[p * 3 + 2];
        const float* Mn = &M[n * 16];
        float zc = Mn[8] * X + Mn[9] * Y + Mn[10] * Z + Mn[11];
        if (zc > 1e-5f) {
            float inv = 1.f / zc;
            float xn = (Mn[0] * X + Mn[1] * Y + Mn[2] * Z + Mn[3]) * inv * (1.f / 704.f);
            float yn = (Mn[4] * X + Mn[5] * Y + Mn[6] * Z + Mn[7]) * inv * (1.f / 256.f);
            int Wl = lWt[l], Hl = lHt[l];
            float px = xn * Wl - 0.5f, py = yn * Hl - 0.5f;
            px = fminf(fmaxf(px, -2.f), (float)(Wl + 1));
            py = fminf(fmaxf(py, -2.f), (float)(Hl + 1));
            float x0f = floorf(px), y0f = floorf(py);
            float wx = px - x0f, wy = py - y0f;
            int x0 = (int)x0f, y0 = (int)y0f;
            bool xi0 = (unsigned)x0 < (unsigned)Wl, xi1 = (unsigned)(x0 + 1) < (unsigned)Wl;
            bool yi0 = (unsigned)y0 < (unsigned)Hl, yi1 = (unsigned)(y0 + 1) < (unsigned)Hl;
            if ((xi0 || xi1) && (yi0 || yi1)) {
                float wl = swl_s[p * 4 + l];
                float w00 = wl * (1.f - wx) * (1.f - wy) * (float)(xi0 && yi0);
                float w10 = wl * wx * (1.f - wy)         * (float)(xi1 && yi0);
                float w01 = wl * (1.f - wx) * wy         * (float)(xi0 && yi1);
                float w11 = wl * wx * wy                 * (float)(xi1 && yi1);
                int x0c = min(max(x0, 0), Wl - 1), x1c = min(max(x0 + 1, 0), Wl - 1);
                int y0c = min(max(y0, 0), Hl - 1), y1c = min(max(y0 + 1, 0), Hl - 1);
                int base = loff[l] + n * Hl * Wl * 128;
                int idx = atomicAdd(&cnt[p], 1);
                offs[p][idx][0] = base + (y0c * Wl + x0c) * 128;
                offs[p][idx][1] = base + (y0c * Wl + x1c) * 128;
                offs[p][idx][2] = base + (y1c * Wl + x0c) * 128;
                offs[p][idx][3] = base + (y1c * Wl + x1c) * 128;
                wts[p][idx][0] = w00; wts[p][idx][1] = w10;
                wts[p][idx][2] = w01; wts[p][idx][3] = w11;
            }
        }
    }
    __syncthreads();

    #pragma unroll 1
    for (int i = 0; i < 4; i++) {
        int p = wv * 4 + i;
        int np = cnt[p];
        floatx2 a = acc[i];
        #pragma unroll 1
        for (int j = 0; j < np; j++) {
            int4   o = *(const int4*)&offs[p][j][0];
            float4 w = *(const float4*)&wts[p][j][0];
            unsigned int v0 = ((const unsigned int*)(featT + o.x))[lane];
            unsigned int v1 = ((const unsigned int*)(featT + o.y))[lane];
            unsigned int v2 = ((const unsigned int*)(featT + o.z))[lane];
            unsigned int v3 = ((const unsigned int*)(featT + o.w))[lane];
            a += bf2x(v0) * w.x;
            a += bf2x(v1) * w.y;
            a += bf2x(v2) * w.z;
            a += bf2x(v3) * w.w;
        }
        acc[i] = a;
    }
    #pragma unroll
    for (int i = 0; i < 4; i++) {
        union { __hip_bfloat16 h[2]; unsigned int u; } pk;
        pk.h[0] = __float2bfloat16(acc[i].x);
        pk.h[1] = __float2bfloat16(acc[i].y);
        *(unsigned int*)&sf[(size_t)pix * 1024 + (wv * 4 + i) * 128 + 2 * lane] = pk.u;
    }
}

extern "C" void kernel_launch(void* const* d_in, const int* in_sizes, int n_in,
                              void* d_out, int out_size, void* d_ws, size_t ws_size,
                              hipStream_t stream)
{
    const float* feat[4] = {(const float*)d_in[0], (const float*)d_in[1],
                            (const float*)d_in[2], (const float*)d_in[3]};
    const float* l2i       = (const float*)d_in[4];
    const float* bev_query = (const float*)d_in[5];
    const float* bev_pos   = (const float*)d_in[6];
    const float* in_w  = (const float*)d_in[7];  const float* in_b  = (const float*)d_in[8];
    const float* off_w = (const float*)d_in[9];  const float* off_b = (const float*)d_in[10];
    const float* sw_w  = (const float*)d_in[11]; const float* sw_b  = (const float*)d_in[12];
    const float* pe_w1 = (const float*)d_in[13]; const float* pe_b1 = (const float*)d_in[14];
    const float* pe_w2 = (const float*)d_in[15]; const float* pe_b2 = (const float*)d_in[16];
    const float* mid_w1 = (const float*)d_in[17]; const float* mid_b1 = (const float*)d_in[18];
    const float* mid_w2 = (const float*)d_in[19]; const float* mid_b2 = (const float*)d_in[20];
    const float* mid_w3 = (const float*)d_in[21]; const float* mid_b3 = (const float*)d_in[22];
    const float* out_w  = (const float*)d_in[23]; const float* out_b  = (const float*)d_in[24];

    float* ws = (float*)d_ws;
    float* fTf = ws;                    // 1,436,160 : transposed feats bf16
    __hip_bfloat16* fT = (__hip_bfloat16*)fTf;
    float* Bb  = fTf + 1436160;         // 2,097,152 : conv out / offsw raw / m3 (CHW)
    float* Cb  = Bb + 2097152;          // 2,097,152 : q0 / conv2 out
    float* Gb  = Cb + 2097152;          // 2,097,152 : q1 (CHW)
    float* Dp  = Gb + 2097152;          //   393,216 : pts
    float* Eb  = Dp + 393216;           //   524,288 : swn
    float* QTf = Eb + 524288;           // 1,081,600 : padded HWC bf16 (130*130*128)
    __hip_bfloat16* qT = (__hip_bfloat16*)QTf;
    float* SFf = QTf + 1081600;         // 8,388,608 : sf bf16 131072x128
    __hip_bfloat16* sfb = (__hip_bfloat16*)SFf;
    float* M1f = SFf + 8388608;         // 4,194,304 : m1 bf16
    __hip_bfloat16* m1b = (__hip_bfloat16*)M1f;
    float* M2f = M1f + 4194304;         // 4,194,304 : m2 bf16
    __hip_bfloat16* m2b = (__hip_bfloat16*)M2f;
    float* WC1 = M2f + 4194304;         //    73,728 : conv1 weights bf16
    __hip_bfloat16* Wcv1 = (__hip_bfloat16*)WC1;
    float* WC2 = WC1 + 73728;           //    73,728 : conv2 weights bf16
    __hip_bfloat16* Wcv2 = (__hip_bfloat16*)WC2;
    float* W1f = WC2 + 73728;           //   262,144
    __hip_bfloat16* Wb1 = (__hip_bfloat16*)W1f;
    float* W2f = W1f + 262144;          //   131,072
    __hip_bfloat16* Wb2 = (__hip_bfloat16*)W2f;
    float* W3f = W2f + 131072;          //    32,768
    __hip_bfloat16* Wb3 = (__hip_bfloat16*)W3f;
    float* WPf = W3f + 32768;           //    16,384 : pe_w2^T bf16
    __hip_bfloat16* Wpe = (__hip_bfloat16*)WPf;
    float* WOf = WPf + 16384;           //     8,192 : offsw packed weight bf16
    __hip_bfloat16* Wof = (__hip_bfloat16*)WOf;
    float* Bof = WOf + 8192;            //       128 : offsw packed bias fp32

    float* q_out = (float*)d_out;
    float* h_out = q_out + 2097152;

    hipMemsetAsync(qT, 0, (size_t)130 * 130 * 128 * sizeof(__hip_bfloat16), stream);

    feat_transpose_all_k<<<11220, 256, 0, stream>>>(feat[0], feat[1], feat[2], feat[3], fT);
    prep_k<<<3840, 256, 0, stream>>>(mid_w1, mid_w2, mid_w3, pe_w2, off_w, off_b, sw_w, sw_b,
                                     in_w, out_w, Wb1, Wb2, Wb3, Wpe, Wof, Bof, Wcv1, Wcv2);

    // conv1: q0 = inorm(bev_query + conv3x3(bev_query))
    chw2hwc_pad_k<<<256, 256, 0, stream>>>(bev_query, qT);
    bgemm_k<64, 64, 0, 1, 1><<<dim3(2, 256), 256, 0, stream>>>(qT, Wcv1, in_b, Bb, bev_query, HW, 1152, 128);
    inorm_k<<<128, 256, 0, stream>>>(Bb, nullptr, Cb);

    // offsets/sample-weights GEMM over center tap of padded q0 + epilogue
    chw2hwc_pad_k<<<256, 256, 0, stream>>>(Cb, qT);
    bgemm_k<64, 64, 0, 1, 1><<<dim3(2, 256), 256, 0, stream>>>(qT + 131 * 128, Wof, Bof, Bb, nullptr, HW, 128, 128);
    offpost_k<<<64, 256, 0, stream>>>(Bb, bev_pos, Dp, Eb, h_out);

    // fused PE (hidden on the fly + MFMA GEMM) -> sf
    pe_bgemm_k<<<1024, 256, 0, stream>>>(Dp, pe_w1, pe_b1, Wpe, pe_b2, sfb);

    // sampling accumulates taps onto sf
    sample_k<<<HW, 128, 0, stream>>>(fT, Dp, Eb, l2i, sfb);

    // mid MLP: 1024 -> 512 gelu -> 512 gelu -> 128 linear (CHW fp32, +q0 residual)
    bgemm_k<128, 128, 1, 0, 0><<<dim3(4, 128), 256, 0, stream>>>(sfb, Wb1, mid_b1, m1b, nullptr, HW, 1024, 512);
    bgemm_k<128, 128, 1, 0, 0><<<dim3(4, 128), 256, 0, stream>>>(m1b, Wb2, mid_b2, m2b, nullptr, HW, 512, 512);
    bgemm_k<64, 64, 0, 1, 0><<<dim3(2, 256), 256, 0, stream>>>(m2b, Wb3, mid_b3, Bb, Cb, HW, 512, 128);
    inorm_k<<<128, 256, 0, stream>>>(Bb, nullptr, Gb);

    // conv2: q = inorm(q1 + conv3x3(q1))
    chw2hwc_pad_k<<<256, 256, 0, stream>>>(Gb, qT);
    bgemm_k<64, 64, 0, 1, 1><<<dim3(2, 256), 256, 0, stream>>>(qT, Wcv2, out_b, Cb, Gb, HW, 1152, 128);
    inorm_k<<<128, 256, 0, stream>>>(Cb, nullptr, q_out);
}